// Round 1
// baseline (163.227 us; speedup 1.0000x reference)
//
#include <hip/hip_runtime.h>

// x: (B=8, T=16, C=256, H=56, W=56) float32, contiguous.
// n_shift = 32, n_fwd = 16.
// out[b,t,c] = x[b,t-1,c]  for c in [0,16)   (0 at t=0)
//            = x[b,t+1,c]  for c in [16,32)  (0 at t=15)
//            = x[b,t,c]    for c >= 32
//
// Vectorized as float4: HW = 3136 floats = 784 float4 per plane;
// time stride = C*HW = 802816 floats = 200704 float4.

#define TS_T      16
#define TS_C      256
#define TS_HW4    784           // (56*56)/4
#define TS_CHW4   (TS_C * TS_HW4)   // 200704 float4 per time step
#define TS_TOTAL4 (8 * TS_T * TS_CHW4) // 25690112 float4 total

__global__ __launch_bounds__(256) void
temporal_shift_kernel(const float4* __restrict__ x, float4* __restrict__ out, int n4) {
    const int stride = gridDim.x * blockDim.x;
    for (int i = blockIdx.x * blockDim.x + threadIdx.x; i < n4; i += stride) {
        const int plane = i / TS_HW4;          // (b,t,c) plane index — magic-mul
        const int c     = plane % TS_C;
        const int t     = (plane / TS_C) % TS_T;
        float4 v;
        if (c < 16) {
            // shift forward in time: take previous frame
            if (t == 0) v = make_float4(0.f, 0.f, 0.f, 0.f);
            else        v = x[i - TS_CHW4];
        } else if (c < 32) {
            // shift backward in time: take next frame
            if (t == TS_T - 1) v = make_float4(0.f, 0.f, 0.f, 0.f);
            else               v = x[i + TS_CHW4];
        } else {
            v = x[i];
        }
        out[i] = v;
    }
}

extern "C" void kernel_launch(void* const* d_in, const int* in_sizes, int n_in,
                              void* d_out, int out_size, void* d_ws, size_t ws_size,
                              hipStream_t stream) {
    const float4* x = (const float4*)d_in[0];
    float4* out = (float4*)d_out;
    const int n4 = TS_TOTAL4;

    // Memory-bound streaming: ~8 blocks/CU on 256 CUs, grid-stride the rest.
    const int block = 256;
    const int grid  = 2048;
    temporal_shift_kernel<<<grid, block, 0, stream>>>(x, out, n4);
}